// Round 8
// baseline (98.608 us; speedup 1.0000x reference)
//
#include <hip/hip_runtime.h>
#include <hip/hip_bf16.h>

typedef __attribute__((ext_vector_type(8))) short bf16x8;
typedef __attribute__((ext_vector_type(4))) float f32x4;

#define B_ 2048
#define S_ 200
#define D_ 128
#define H_ 64
#define NT 13
#define LOG2E 1.44269504f

// ws layout
#define WS_TA 0                       // f32 tA[2048][64]   = 512 KB
#define WS_BC (512*1024)              // f32 bcT[64][128]   = 32 KB  (W1b - W1c, transposed)
#define WS_DT (512*1024 + 32768)      // f32 dT [64][128]   = 32 KB  (W1d, transposed)

static __device__ __forceinline__ short f2bf_hw(float f) {
    return (short)__builtin_bit_cast(unsigned short, __float2bfloat16(f));  // RNE
}

// ---- prep: exact fp32 tA[b][n] = t.(W1a+W1c)+b1 ; transpose folded weights ----
__global__ __launch_bounds__(256)
void prep_kernel(const float* __restrict__ tgt, const float* __restrict__ W1,
                 const float* __restrict__ b1, char* __restrict__ ws)
{
    __shared__ float tl[16][128];
    const int tid = threadIdx.x;
    const int b0 = blockIdx.x * 16;
    for (int i = tid; i < 512; i += 256) {
        int bb = i >> 5, q = i & 31;
        *(float4*)&tl[bb][q * 4] = *(const float4*)(tgt + (size_t)(b0 + bb) * D_ + q * 4);
    }
    __syncthreads();
    const int n = tid & 63;
    const int bb0 = (tid >> 6) * 4;
    float a0 = 0.f, a1 = 0.f, a2 = 0.f, a3 = 0.f;
    for (int d = 0; d < 128; ++d) {
        float wsum = W1[d * H_ + n] + W1[(256 + d) * H_ + n];  // W1a + W1c
        a0 = fmaf(tl[bb0 + 0][d], wsum, a0);
        a1 = fmaf(tl[bb0 + 1][d], wsum, a1);
        a2 = fmaf(tl[bb0 + 2][d], wsum, a2);
        a3 = fmaf(tl[bb0 + 3][d], wsum, a3);
    }
    const float bn = b1[n];
    float* tA = (float*)(ws + WS_TA);
    tA[(size_t)(b0 + bb0 + 0) * H_ + n] = a0 + bn;
    tA[(size_t)(b0 + bb0 + 1) * H_ + n] = a1 + bn;
    tA[(size_t)(b0 + bb0 + 2) * H_ + n] = a2 + bn;
    tA[(size_t)(b0 + bb0 + 3) * H_ + n] = a3 + bn;

    if (blockIdx.x == 0) {
        float* bcT = (float*)(ws + WS_BC);
        float* dT  = (float*)(ws + WS_DT);
        for (int i = tid; i < 8192; i += 256) {
            int nn = i >> 7, k = i & 127;
            bcT[nn * 128 + k] = W1[(128 + k) * H_ + nn] - W1[(256 + k) * H_ + nn];
            dT [nn * 128 + k] = W1[(384 + k) * H_ + nn];
        }
    }
}

// ---- fused: ONE WAVE PER BATCH; barrier-free; swapped-operand MFMA flash ----
// amdgpu_waves_per_eu(2,2): LDS (64KB) caps residency at 2 blocks/CU = 2 waves/EU
// anyway; pinning max=2 raises the VGPR budget to 256 so the ~195-reg live set
// does NOT spill (R7: allocator targeted 4 waves/EU -> 128 VGPR -> 19MB scratch
// writes + occupancy throttled to 0.7%).
__global__ __launch_bounds__(256) __attribute__((amdgpu_waves_per_eu(2, 2)))
void din_fused(const float* __restrict__ tgt, const float* __restrict__ hist,
               const int* __restrict__ mask, const float* __restrict__ W2,
               const char* __restrict__ ws, float* __restrict__ out)
{
    __shared__ __align__(16) char wt[4][16384];   // per-wave swizzled bf16 W''^T [n=64][k=128]

    const int tid  = threadIdx.x;
    const int lane = tid & 63;
    const int wv   = tid >> 6;
    const int b    = blockIdx.x * 4 + wv;         // one batch per wave
    const int lo   = lane & 15;
    const int hi   = lane >> 4;
    char* mywt = wt[wv];

    // ---- issue first two history tiles early (independent of the build) ----
    f32x4 stA[4][2], stB[4][2];
    int mAv, mBv;
    auto loadt = [&](f32x4 (&st)[4][2], int& mv, int t) {
        int srow = (t << 4) + lo;
        int sc = srow > S_ - 1 ? S_ - 1 : srow;
        const float* hp = hist + ((size_t)b * S_ + sc) * D_ + hi * 8;
        #pragma unroll
        for (int ks = 0; ks < 4; ++ks) {
            st[ks][0] = *(const f32x4*)(hp + ks * 32);
            st[ks][1] = *(const f32x4*)(hp + ks * 32 + 4);
        }
        mv = (srow < S_) ? mask[(size_t)b * S_ + sc] : 0;
    };
    loadt(stA, mAv, 0);
    loadt(stB, mBv, 1);

    // ---- wave-local W'' build: lane owns kb = lo (8 k's), rows n = hi*16+j ----
    // W''[k][n] = (W1b-W1c)[k][n] + t[k]*W1d[k][n], bf16, [n][k] XOR-swizzled
    {
        const float* bcT = (const float*)(ws + WS_BC);
        const float* dT  = (const float*)(ws + WS_DT);
        const int kb = lo;                        // fixed k-octet per lane
        f32x4 t0 = *(const f32x4*)(tgt + (size_t)b * D_ + kb * 8);
        f32x4 t1 = *(const f32x4*)(tgt + (size_t)b * D_ + kb * 8 + 4);
        #pragma unroll 4
        for (int j = 0; j < 16; ++j) {
            int n = hi * 16 + j;
            f32x4 bc0 = *(const f32x4*)(bcT + n * 128 + kb * 8);
            f32x4 bc1 = *(const f32x4*)(bcT + n * 128 + kb * 8 + 4);
            f32x4 dd0 = *(const f32x4*)(dT  + n * 128 + kb * 8);
            f32x4 dd1 = *(const f32x4*)(dT  + n * 128 + kb * 8 + 4);
            bf16x8 v;
            #pragma unroll
            for (int e = 0; e < 4; ++e) {
                v[e]     = f2bf_hw(fmaf(t0[e], dd0[e], bc0[e]));
                v[e + 4] = f2bf_hw(fmaf(t1[e], dd1[e], bc1[e]));
            }
            int byteoff = (n * 256 + kb * 16) ^ ((n & 7) << 4);
            *(bf16x8*)(mywt + byteoff) = v;
        }
    }
    // in-wave ds_write -> ds_read ordering is guaranteed via lgkmcnt; no barrier.

    // per-lane constants for n = ng*16 + hi*4 + e (swapped-D layout)
    f32x4 tav[4], w2v[4];
    #pragma unroll
    for (int ng = 0; ng < 4; ++ng) {
        tav[ng] = *(const f32x4*)((const float*)(ws + WS_TA) + (size_t)b * H_ + ng * 16 + hi * 4);
        f32x4 wv4 = *(const f32x4*)(W2 + ng * 16 + hi * 4);
        w2v[ng] = (f32x4){wv4[0] * LOG2E, wv4[1] * LOG2E, wv4[2] * LOG2E, wv4[3] * LOG2E};
    }

    // A-operand (W'') swizzled LDS offsets: addr = vbase[ng] + koff[ks]
    int vbase[4], koff[4];
    #pragma unroll
    for (int ng = 0; ng < 4; ++ng) vbase[ng] = (ng * 16 + lo) * 256;
    #pragma unroll
    for (int ks = 0; ks < 4; ++ks) koff[ks] = (ks * 64 + hi * 16) ^ ((lo & 7) << 4);

    float o[4][8];
    #pragma unroll
    for (int ks = 0; ks < 4; ++ks)
        #pragma unroll
        for (int e = 0; e < 8; ++e) o[ks][e] = 0.f;
    float l = 0.f, m2 = -1e30f;

    auto compt = [&](f32x4 (&st)[4][2], int mv, int t) {
        // fp32 -> bf16 B fragments (history)
        bf16x8 bfr[4];
        #pragma unroll
        for (int ks = 0; ks < 4; ++ks)
            #pragma unroll
            for (int e = 0; e < 4; ++e) {
                bfr[ks][e]     = f2bf_hw(st[ks][0][e]);
                bfr[ks][e + 4] = f2bf_hw(st[ks][1][e]);
            }
        // swapped MFMA: D[n,s]; A = W''^T frags (wave-local LDS), B = history frags
        f32x4 acc[4];
        #pragma unroll
        for (int ng = 0; ng < 4; ++ng) acc[ng] = (f32x4){0.f, 0.f, 0.f, 0.f};
        #pragma unroll
        for (int ks = 0; ks < 4; ++ks)
            #pragma unroll
            for (int ng = 0; ng < 4; ++ng) {
                bf16x8 afrag = *(const bf16x8*)(mywt + vbase[ng] + koff[ks]);
                acc[ng] = __builtin_amdgcn_mfma_f32_16x16x32_bf16(afrag, bfr[ks], acc[ng], 0, 0, 0);
            }
        // lane-local relu-dot over 16 n-values (tree to cut chain depth)
        float s0 = 0.f, s1 = 0.f, s2 = 0.f, s3 = 0.f;
        #pragma unroll
        for (int e = 0; e < 4; ++e) {
            s0 = fmaf(fmaxf(acc[0][e] + tav[0][e], 0.f), w2v[0][e], s0);
            s1 = fmaf(fmaxf(acc[1][e] + tav[1][e], 0.f), w2v[1][e], s1);
            s2 = fmaf(fmaxf(acc[2][e] + tav[2][e], 0.f), w2v[2][e], s2);
            s3 = fmaf(fmaxf(acc[3][e] + tav[3][e], 0.f), w2v[3][e], s3);
        }
        float sum = (s0 + s1) + (s2 + s3);
        // n-sum across the 4 hi groups: 2 butterflies -> uniform across hi
        sum += __shfl_xor(sum, 16);
        sum += __shfl_xor(sum, 32);
        float lg = mv ? sum : -1e30f;
        // tile max over the 16 lo-lanes -> wave-uniform
        float tm = lg;
        tm = fmaxf(tm, __shfl_xor(tm, 1));
        tm = fmaxf(tm, __shfl_xor(tm, 2));
        tm = fmaxf(tm, __shfl_xor(tm, 4));
        tm = fmaxf(tm, __shfl_xor(tm, 8));
        if (tm > m2 + 11.5f) {                 // defer-rescale (T13)
            float r = exp2f(m2 - tm);
            #pragma unroll
            for (int ks = 0; ks < 4; ++ks)
                #pragma unroll
                for (int e = 0; e < 8; ++e) o[ks][e] *= r;
            l *= r;
            m2 = tm;
        }
        float p = mv ? exp2f(lg - m2) : 0.f;
        l += p;
        #pragma unroll
        for (int ks = 0; ks < 4; ++ks) {
            o[ks][0] = fmaf(p, st[ks][0][0], o[ks][0]);
            o[ks][1] = fmaf(p, st[ks][0][1], o[ks][1]);
            o[ks][2] = fmaf(p, st[ks][0][2], o[ks][2]);
            o[ks][3] = fmaf(p, st[ks][0][3], o[ks][3]);
            o[ks][4] = fmaf(p, st[ks][1][0], o[ks][4]);
            o[ks][5] = fmaf(p, st[ks][1][1], o[ks][5]);
            o[ks][6] = fmaf(p, st[ks][1][2], o[ks][6]);
            o[ks][7] = fmaf(p, st[ks][1][3], o[ks][7]);
        }
    };

    // ---- 13-tile deep pipeline, register double-buffered ----
    #pragma unroll 1
    for (int t = 0; t < 12; t += 2) {
        compt(stA, mAv, t);
        if (t + 2 < NT) loadt(stA, mAv, t + 2);
        compt(stB, mBv, t + 1);
        if (t + 3 < NT) loadt(stB, mBv, t + 3);
    }
    compt(stA, mAv, 12);

    // deferred reduce over the 16 lo-lanes
    #pragma unroll
    for (int ks = 0; ks < 4; ++ks)
        #pragma unroll
        for (int e = 0; e < 8; ++e) {
            float v = o[ks][e];
            v += __shfl_xor(v, 1);
            v += __shfl_xor(v, 2);
            v += __shfl_xor(v, 4);
            v += __shfl_xor(v, 8);
            o[ks][e] = v;
        }
    l += __shfl_xor(l, 1);
    l += __shfl_xor(l, 2);
    l += __shfl_xor(l, 4);
    l += __shfl_xor(l, 8);

    // direct stores: lanes lo==0 hold d = ks*32 + hi*8 + e ; m2 cancels, b2 cancels
    const float inv = 1.0f / l;
    if (lo == 0) {
        float* op = out + (size_t)b * D_ + hi * 8;
        #pragma unroll
        for (int ks = 0; ks < 4; ++ks) {
            f32x4 v0 = {o[ks][0] * inv, o[ks][1] * inv, o[ks][2] * inv, o[ks][3] * inv};
            f32x4 v1 = {o[ks][4] * inv, o[ks][5] * inv, o[ks][6] * inv, o[ks][7] * inv};
            *(f32x4*)(op + ks * 32)     = v0;
            *(f32x4*)(op + ks * 32 + 4) = v1;
        }
    }
}

extern "C" void kernel_launch(void* const* d_in, const int* in_sizes, int n_in,
                              void* d_out, int out_size, void* d_ws, size_t ws_size,
                              hipStream_t stream) {
    const float* tgt  = (const float*)d_in[0];
    const float* hist = (const float*)d_in[1];
    const int*   mask = (const int*)d_in[2];
    const float* W1   = (const float*)d_in[3];
    const float* b1   = (const float*)d_in[4];
    const float* W2   = (const float*)d_in[5];
    const float* b2   = (const float*)d_in[6];
    (void)b2;  // cancels in softmax
    float* out = (float*)d_out;
    char* ws = (char*)d_ws;

    prep_kernel<<<128, 256, 0, stream>>>(tgt, W1, b1, ws);
    din_fused<<<B_ / 4, 256, 0, stream>>>(tgt, hist, mask, W2, ws, out);
}

// Round 9
// 69.578 us; speedup vs baseline: 1.4172x; 1.4172x over previous
//
#include <hip/hip_runtime.h>
#include <hip/hip_bf16.h>

typedef __attribute__((ext_vector_type(8))) short bf16x8;
typedef __attribute__((ext_vector_type(4))) float f32x4;

#define B_ 2048
#define S_ 200
#define D_ 128
#define H_ 64
#define NT 13
#define LOG2E 1.44269504f

// ws layout
#define WS_TA 0u                        // f32 tA[2048][64]          = 512 KB
#define WS_AC (512u*1024u)              // f32 acT[64][128] (W1a+W1c)=  32 KB
#define WS_BC (512u*1024u + 32768u)     // f32 bcT[64][128] (W1b-W1c)=  32 KB
#define WS_DT (512u*1024u + 65536u)     // f32 dT [64][128] (W1d)    =  32 KB
#define WS_WF (512u*1024u + 98304u)     // bf16 W'' frag image [2048][16384 B] = 32 MB

static __device__ __forceinline__ short f2bf_hw(float f) {
    return (short)__builtin_bit_cast(unsigned short, __float2bfloat16(f));  // RNE
}

static __device__ __forceinline__ void gload16(const void* g, void* l) {
    // dest = lds_base(wave-uniform) + lane*16 ; global addr is per-lane
    __builtin_amdgcn_global_load_lds(
        (const __attribute__((address_space(1))) unsigned int*)g,
        (__attribute__((address_space(3))) unsigned int*)l, 16, 0, 0);
}

// ---- prep A: fold + transpose W1 into acT/bcT/dT (k-contiguous) ----
__global__ __launch_bounds__(128)
void prep_fold(const float* __restrict__ W1, char* __restrict__ ws)
{
    const int n = blockIdx.x;       // 64 blocks
    const int k = threadIdx.x;      // 128 threads
    float a = W1[k * H_ + n];
    float b = W1[(128 + k) * H_ + n];
    float c = W1[(256 + k) * H_ + n];
    float d = W1[(384 + k) * H_ + n];
    ((float*)(ws + WS_AC))[n * 128 + k] = a + c;
    ((float*)(ws + WS_BC))[n * 128 + k] = b - c;
    ((float*)(ws + WS_DT))[n * 128 + k] = d;
}

// ---- prep B: per batch, exact fp32 tA and the swizzled bf16 W'' LDS image ----
// LDS image byte y (0..16383): n = y>>8 ; k-octet kk = ((y>>4)&15) ^ (n&7)
// so that the fused read addr (n*256 + kb*16) ^ ((n&7)<<4) returns octet kb.
__global__ __launch_bounds__(256)
void prep_batch(const float* __restrict__ tgt, const float* __restrict__ b1,
                char* __restrict__ ws)
{
    __shared__ float tl[128];
    __shared__ float part[4][64];
    const int b = blockIdx.x;
    const int tid = threadIdx.x;
    if (tid < 32)
        *(float4*)&tl[tid * 4] = ((const float4*)(tgt + (size_t)b * D_))[tid];
    __syncthreads();

    // tA[b][n] = sum_d t[d]*(W1a+W1c)[d][n] + b1[n]   (exact fp32)
    {
        const int n = tid & 63, q = tid >> 6;
        const float* ac = (const float*)(ws + WS_AC) + n * 128 + q * 32;
        float s = 0.f;
        #pragma unroll 8
        for (int i = 0; i < 32; ++i) s = fmaf(tl[q * 32 + i], ac[i], s);
        part[q][n] = s;
    }
    __syncthreads();
    if (tid < 64)
        ((float*)(ws + WS_TA))[(size_t)b * H_ + tid] =
            part[0][tid] + part[1][tid] + part[2][tid] + part[3][tid] + b1[tid];

    // W''[k][n] = bc[k][n] + t[k]*d[k][n] -> bf16 chunks in swizzled image order
    unsigned short* wf = (unsigned short*)(ws + WS_WF + (size_t)b * 16384u);
    #pragma unroll
    for (int j = 0; j < 4; ++j) {
        int c = tid + j * 256;              // chunk id = byte offset / 16
        int nn = c >> 4;
        int kk = (c & 15) ^ (nn & 7);
        int k0 = kk * 8;
        const float* bc = (const float*)(ws + WS_BC) + nn * 128 + k0;
        const float* dd = (const float*)(ws + WS_DT) + nn * 128 + k0;
        bf16x8 v;
        #pragma unroll
        for (int e = 0; e < 8; ++e)
            v[e] = f2bf_hw(fmaf(tl[k0 + e], dd[e], bc[e]));
        *(bf16x8*)(wf + c * 8) = v;
    }
}

// ---- fused: one wave per batch; LDS-staged pipeline, vmcnt-counted ----
// Per-wave LDS slice (32 KB): [0,16K) W'' ; [16K,24K) hist buf0 ; [24K,32K) buf1.
__global__ __launch_bounds__(128, 2)
void din_fused(const float* __restrict__ hist, const int* __restrict__ mask,
               const float* __restrict__ W2, const char* __restrict__ ws,
               float* __restrict__ out)
{
    __shared__ __align__(16) char lds[65536];
    const int tid  = threadIdx.x;
    const int lane = tid & 63;
    const int wv   = tid >> 6;
    const int b    = blockIdx.x * 2 + wv;
    const int lo   = lane & 15;
    const int hi   = lane >> 4;
    char* L = lds + wv * 32768;

    // --- prologue register loads (issued before the gll stream) ---
    int mraw[NT];
    {
        const int* mp = mask + (size_t)b * S_;
        #pragma unroll
        for (int t = 0; t < NT; ++t) {
            int s = lo + 16 * t;
            mraw[t] = (s < S_) ? mp[s] : 0;
        }
    }
    f32x4 tav[4], w2v[4];
    #pragma unroll
    for (int ng = 0; ng < 4; ++ng) {
        tav[ng] = *(const f32x4*)((const float*)(ws + WS_TA) + (size_t)b * H_ + ng * 16 + hi * 4);
        w2v[ng] = *(const f32x4*)(W2 + ng * 16 + hi * 4);
    }

    // --- W'' image -> wave LDS (16 x 1KB, linear) ---
    {
        const char* src = ws + WS_WF + (size_t)b * 16384u + (size_t)lane * 16u;
        #pragma unroll
        for (int i = 0; i < 16; ++i)
            gload16(src + i * 1024, L + i * 1024);
    }

    // --- history tile stage: linear LDS dest, inverse-swizzled global source ---
    const char* hb = (const char*)hist + (size_t)b * (S_ * D_ * 4);
    const int cp = (lane & 31) * 16;
    const int h5 = lane >> 5;
    auto stage = [&](int t, int bufo) {
        #pragma unroll
        for (int i = 0; i < 8; ++i) {
            int r = 2 * i + h5;
            int s = (t << 4) + r;
            s = s > S_ - 1 ? S_ - 1 : s;
            gload16(hb + s * 512 + (cp ^ ((r & 7) << 4)), L + bufo + i * 1024);
        }
    };
    stage(0, 16384);
    stage(1, 24576);

    // --- consume prologue regs (compiler waits count the glls correctly) ---
    int mbits = 0;
    #pragma unroll
    for (int t = 0; t < NT; ++t) mbits |= (mraw[t] != 0) << t;
    #pragma unroll
    for (int ng = 0; ng < 4; ++ng)
        w2v[ng] = (f32x4){w2v[ng][0] * LOG2E, w2v[ng][1] * LOG2E,
                          w2v[ng][2] * LOG2E, w2v[ng][3] * LOG2E};

    // swizzled read offsets
    int abase[4], akoff[4];
    #pragma unroll
    for (int ng = 0; ng < 4; ++ng) abase[ng] = (ng * 16 + lo) * 256;
    #pragma unroll
    for (int ks = 0; ks < 4; ++ks) akoff[ks] = (ks * 64 + hi * 16) ^ ((lo & 7) << 4);
    const int rb = (lo * 512 + hi * 32) ^ ((lo & 7) << 4);

    float o[4][8];
    #pragma unroll
    for (int ks = 0; ks < 4; ++ks)
        #pragma unroll
        for (int e = 0; e < 8; ++e) o[ks][e] = 0.f;
    float l = 0.f, m2 = -1e30f;

    auto compt = [&](int t, int bufo, bool dostage) {
        // fp32 history from LDS (swizzled read)
        f32x4 h0[4], h1[4];
        #pragma unroll
        for (int ks = 0; ks < 4; ++ks) {
            int off = bufo + rb + ks * 128;
            h0[ks] = *(const f32x4*)(L + off);
            h1[ks] = *(const f32x4*)(L + (off ^ 16));
        }
        // reads done -> safe to overwrite this buffer with tile t+2
        asm volatile("s_waitcnt lgkmcnt(0)" ::: "memory");
        __builtin_amdgcn_sched_barrier(0);
        if (dostage) stage(t + 2, bufo);

        // bf16 B fragments (history)
        bf16x8 bfr[4];
        #pragma unroll
        for (int ks = 0; ks < 4; ++ks)
            #pragma unroll
            for (int e = 0; e < 4; ++e) {
                bfr[ks][e]     = f2bf_hw(h0[ks][e]);
                bfr[ks][e + 4] = f2bf_hw(h1[ks][e]);
            }
        // swapped MFMA: D[n,s]; A = W'' frags (wave LDS), B = history frags
        f32x4 acc[4];
        #pragma unroll
        for (int ng = 0; ng < 4; ++ng) acc[ng] = (f32x4){0.f, 0.f, 0.f, 0.f};
        #pragma unroll
        for (int ks = 0; ks < 4; ++ks)
            #pragma unroll
            for (int ng = 0; ng < 4; ++ng) {
                bf16x8 af = *(const bf16x8*)(L + abase[ng] + akoff[ks]);
                acc[ng] = __builtin_amdgcn_mfma_f32_16x16x32_bf16(af, bfr[ks], acc[ng], 0, 0, 0);
            }
        // lane-local relu-dot over this lane's 16 n-values; s = t*16+lo
        float s0 = 0.f, s1 = 0.f, s2 = 0.f, s3 = 0.f;
        #pragma unroll
        for (int e = 0; e < 4; ++e) {
            s0 = fmaf(fmaxf(acc[0][e] + tav[0][e], 0.f), w2v[0][e], s0);
            s1 = fmaf(fmaxf(acc[1][e] + tav[1][e], 0.f), w2v[1][e], s1);
            s2 = fmaf(fmaxf(acc[2][e] + tav[2][e], 0.f), w2v[2][e], s2);
            s3 = fmaf(fmaxf(acc[3][e] + tav[3][e], 0.f), w2v[3][e], s3);
        }
        float sum = (s0 + s1) + (s2 + s3);
        sum += __shfl_xor(sum, 16);
        sum += __shfl_xor(sum, 32);
        const int mv = (mbits >> t) & 1;
        float lg = mv ? sum : -1e30f;
        float tm = lg;
        tm = fmaxf(tm, __shfl_xor(tm, 1));
        tm = fmaxf(tm, __shfl_xor(tm, 2));
        tm = fmaxf(tm, __shfl_xor(tm, 4));
        tm = fmaxf(tm, __shfl_xor(tm, 8));
        if (tm > m2 + 11.5f) {                 // defer-rescale (T13)
            float r = exp2f(m2 - tm);
            #pragma unroll
            for (int ks = 0; ks < 4; ++ks)
                #pragma unroll
                for (int e = 0; e < 8; ++e) o[ks][e] *= r;
            l *= r;
            m2 = tm;
        }
        float p = mv ? exp2f(lg - m2) : 0.f;
        l += p;
        #pragma unroll
        for (int ks = 0; ks < 4; ++ks) {
            o[ks][0] = fmaf(p, h0[ks][0], o[ks][0]);
            o[ks][1] = fmaf(p, h0[ks][1], o[ks][1]);
            o[ks][2] = fmaf(p, h0[ks][2], o[ks][2]);
            o[ks][3] = fmaf(p, h0[ks][3], o[ks][3]);
            o[ks][4] = fmaf(p, h1[ks][0], o[ks][4]);
            o[ks][5] = fmaf(p, h1[ks][1], o[ks][5]);
            o[ks][6] = fmaf(p, h1[ks][2], o[ks][6]);
            o[ks][7] = fmaf(p, h1[ks][3], o[ks][7]);
        }
    };

    // --- 13-tile pipeline: counted vmcnt, never drained to 0 until the tail ---
    #pragma unroll 1
    for (int t = 0; t < 12; ++t) {
        asm volatile("s_waitcnt vmcnt(8)" ::: "memory");   // tile t landed; t+1 in flight
        compt(t, 16384 + ((t & 1) << 13), t + 2 < NT);
    }
    asm volatile("s_waitcnt vmcnt(0)" ::: "memory");
    compt(12, 16384, false);

    // --- epilogue: reduce over the 16 lo-lanes, direct stores ---
    #pragma unroll
    for (int ks = 0; ks < 4; ++ks)
        #pragma unroll
        for (int e = 0; e < 8; ++e) {
            float v = o[ks][e];
            v += __shfl_xor(v, 1);
            v += __shfl_xor(v, 2);
            v += __shfl_xor(v, 4);
            v += __shfl_xor(v, 8);
            o[ks][e] = v;
        }
    l += __shfl_xor(l, 1);
    l += __shfl_xor(l, 2);
    l += __shfl_xor(l, 4);
    l += __shfl_xor(l, 8);

    const float inv = 1.0f / l;                 // m2, b2 cancel in softmax
    if (lo == 0) {
        float* op = out + (size_t)b * D_ + hi * 8;
        #pragma unroll
        for (int ks = 0; ks < 4; ++ks) {
            f32x4 v0 = {o[ks][0] * inv, o[ks][1] * inv, o[ks][2] * inv, o[ks][3] * inv};
            f32x4 v1 = {o[ks][4] * inv, o[ks][5] * inv, o[ks][6] * inv, o[ks][7] * inv};
            *(f32x4*)(op + ks * 32)     = v0;
            *(f32x4*)(op + ks * 32 + 4) = v1;
        }
    }
}

extern "C" void kernel_launch(void* const* d_in, const int* in_sizes, int n_in,
                              void* d_out, int out_size, void* d_ws, size_t ws_size,
                              hipStream_t stream) {
    const float* tgt  = (const float*)d_in[0];
    const float* hist = (const float*)d_in[1];
    const int*   mask = (const int*)d_in[2];
    const float* W1   = (const float*)d_in[3];
    const float* b1   = (const float*)d_in[4];
    const float* W2   = (const float*)d_in[5];
    const float* b2   = (const float*)d_in[6];
    (void)b2;  // cancels in softmax
    float* out = (float*)d_out;
    char* ws = (char*)d_ws;

    prep_fold<<<64, 128, 0, stream>>>(W1, ws);
    prep_batch<<<B_, 256, 0, stream>>>(tgt, b1, ws);
    din_fused<<<B_ / 2, 128, 0, stream>>>(hist, mask, W2, ws, out);
}

// Round 10
// 68.518 us; speedup vs baseline: 1.4392x; 1.0155x over previous
//
#include <hip/hip_runtime.h>
#include <hip/hip_bf16.h>

typedef __attribute__((ext_vector_type(8))) short bf16x8;
typedef __attribute__((ext_vector_type(4))) float f32x4;

#define B_ 2048
#define S_ 200
#define D_ 128
#define H_ 64
#define NT 13
#define LOG2E 1.44269504f

// ws layout (no more W'' image)
#define WS_TA 0u                        // f32 tA[2048][64]          = 512 KB
#define WS_AC (512u*1024u)              // f32 acT[64][128] (W1a+W1c)=  32 KB
#define WS_BC (512u*1024u + 32768u)     // f32 bcT[64][128] (W1b-W1c)=  32 KB
#define WS_DT (512u*1024u + 65536u)     // f32 dT [64][128] (W1d)    =  32 KB

static __device__ __forceinline__ short f2bf_hw(float f) {
    return (short)__builtin_bit_cast(unsigned short, __float2bfloat16(f));  // RNE
}

static __device__ __forceinline__ void gload16(const void* g, void* l) {
    // LDS dest = wave-uniform base + lane*16 ; global addr is per-lane
    __builtin_amdgcn_global_load_lds(
        (const __attribute__((address_space(1))) unsigned int*)g,
        (__attribute__((address_space(3))) unsigned int*)l, 16, 0, 0);
}

// ---- prep A: fold + transpose W1 into acT/bcT/dT (k-contiguous) ----
__global__ __launch_bounds__(128)
void prep_fold(const float* __restrict__ W1, char* __restrict__ ws)
{
    const int n = blockIdx.x;       // 64 blocks
    const int k = threadIdx.x;      // 128 threads
    float a = W1[k * H_ + n];
    float b = W1[(128 + k) * H_ + n];
    float c = W1[(256 + k) * H_ + n];
    float d = W1[(384 + k) * H_ + n];
    ((float*)(ws + WS_AC))[n * 128 + k] = a + c;
    ((float*)(ws + WS_BC))[n * 128 + k] = b - c;
    ((float*)(ws + WS_DT))[n * 128 + k] = d;
}

// ---- prep B: exact fp32 tA[b][n] = t.(W1a+W1c) + b1 ; 4 batches per block ----
__global__ __launch_bounds__(256)
void prep_ta(const float* __restrict__ tgt, const float* __restrict__ b1,
             char* __restrict__ ws)
{
    __shared__ float tl[4][128];
    const int tid = threadIdx.x;
    const int b0 = blockIdx.x * 4;
    if (tid < 128) {
        int bb = tid >> 5, q = tid & 31;
        *(float4*)&tl[bb][q * 4] = ((const float4*)(tgt + (size_t)(b0 + bb) * D_))[q];
    }
    __syncthreads();
    const int n = tid & 63, bb = tid >> 6;
    const float* ac = (const float*)(ws + WS_AC) + n * 128;
    float s = 0.f;
    #pragma unroll 8
    for (int d = 0; d < 128; ++d) s = fmaf(tl[bb][d], ac[d], s);
    ((float*)(ws + WS_TA))[(size_t)(b0 + bb) * H_ + n] = s + b1[n];
}

// ---- fused: one 64-thread block per batch; in-kernel W'' build; 3-deep pipeline ----
// LDS (40 KB): [0,16K) W'' swizzled ; hist bufs at 16K / 24K / 32K (8 KB each).
__global__ __launch_bounds__(64, 2)
void din_fused(const float* __restrict__ tgt, const float* __restrict__ hist,
               const int* __restrict__ mask, const float* __restrict__ W2,
               const char* __restrict__ ws, float* __restrict__ out)
{
    __shared__ __align__(16) char L[40960];
    const int lane = threadIdx.x;          // 0..63 (one wave)
    const int b    = blockIdx.x;
    const int lo   = lane & 15;
    const int hi   = lane >> 4;

    // --- prologue register loads (compiler-managed; consumed before stage glls) ---
    int mraw[NT];
    {
        const int* mp = mask + (size_t)b * S_;
        #pragma unroll
        for (int t = 0; t < NT; ++t) {
            int s = lo + 16 * t;
            mraw[t] = (s < S_) ? mp[s] : 0;
        }
    }
    f32x4 tav[4], w2v[4];
    #pragma unroll
    for (int ng = 0; ng < 4; ++ng) {
        tav[ng] = *(const f32x4*)((const float*)(ws + WS_TA) + (size_t)b * H_ + ng * 16 + hi * 4);
        w2v[ng] = *(const f32x4*)(W2 + ng * 16 + hi * 4);
    }

    // --- in-kernel W'' build (L2-hot tables); all loads reg-consumed here so the
    //     hand-counted vmcnt below tracks ONLY the stage glls ---
    // W''[k][n] = (W1b-W1c)[k][n] + t[k]*W1d[k][n], bf16, [n][k] XOR-swizzled.
    {
        const float* bcT = (const float*)(ws + WS_BC);
        const float* dT  = (const float*)(ws + WS_DT);
        const int kb = lo;                 // lane owns k-octet kb
        f32x4 t0 = *(const f32x4*)(tgt + (size_t)b * D_ + kb * 8);
        f32x4 t1 = *(const f32x4*)(tgt + (size_t)b * D_ + kb * 8 + 4);
        #pragma unroll 2
        for (int j = 0; j < 16; ++j) {
            int n = hi * 16 + j;
            f32x4 bc0 = *(const f32x4*)(bcT + n * 128 + kb * 8);
            f32x4 bc1 = *(const f32x4*)(bcT + n * 128 + kb * 8 + 4);
            f32x4 dd0 = *(const f32x4*)(dT  + n * 128 + kb * 8);
            f32x4 dd1 = *(const f32x4*)(dT  + n * 128 + kb * 8 + 4);
            bf16x8 v;
            #pragma unroll
            for (int e = 0; e < 4; ++e) {
                v[e]     = f2bf_hw(fmaf(t0[e], dd0[e], bc0[e]));
                v[e + 4] = f2bf_hw(fmaf(t1[e], dd1[e], bc1[e]));
            }
            int byteoff = n * 256 + ((kb * 16) ^ ((n & 7) << 4));
            *(bf16x8*)(L + byteoff) = v;
        }
    }

    // consume prologue regs
    int mbits = 0;
    #pragma unroll
    for (int t = 0; t < NT; ++t) mbits |= (mraw[t] != 0) << t;
    #pragma unroll
    for (int ng = 0; ng < 4; ++ng)
        w2v[ng] = (f32x4){w2v[ng][0] * LOG2E, w2v[ng][1] * LOG2E,
                          w2v[ng][2] * LOG2E, w2v[ng][3] * LOG2E};

    // --- history tile stage: linear LDS dest, inverse-swizzled global source ---
    const char* hb = (const char*)hist + (size_t)b * (S_ * D_ * 4);
    const int cp = (lane & 31) * 16;
    const int h5 = lane >> 5;
    auto stage = [&](int t, int bufo) {
        #pragma unroll
        for (int i = 0; i < 8; ++i) {
            int r = 2 * i + h5;
            int s = (t << 4) + r;
            s = s > S_ - 1 ? S_ - 1 : s;
            gload16(hb + s * 512 + (cp ^ ((r & 7) << 4)), L + bufo + i * 1024);
        }
    };
    stage(0, 16384);
    stage(1, 24576);
    stage(2, 32768);

    // swizzled read offsets
    int abase[4], akoff[4];
    #pragma unroll
    for (int ng = 0; ng < 4; ++ng) abase[ng] = (ng * 16 + lo) * 256;
    #pragma unroll
    for (int ks = 0; ks < 4; ++ks) akoff[ks] = (ks * 64 + hi * 16) ^ ((lo & 7) << 4);
    const int rb = (lo * 512 + hi * 32) ^ ((lo & 7) << 4);

    float o[4][8];
    #pragma unroll
    for (int ks = 0; ks < 4; ++ks)
        #pragma unroll
        for (int e = 0; e < 8; ++e) o[ks][e] = 0.f;
    float l = 0.f, m2 = -1e30f;

    auto compt = [&](int t, int bufo, bool dostage) {
        // fp32 history from LDS (swizzled read)
        f32x4 h0[4], h1[4];
        #pragma unroll
        for (int ks = 0; ks < 4; ++ks) {
            int off = bufo + rb + ks * 128;
            h0[ks] = *(const f32x4*)(L + off);
            h1[ks] = *(const f32x4*)(L + (off ^ 16));
        }
        // reads done -> safe to overwrite this buffer with tile t+3
        asm volatile("s_waitcnt lgkmcnt(0)" ::: "memory");
        __builtin_amdgcn_sched_barrier(0);
        if (dostage) stage(t + 3, bufo);

        // bf16 B fragments (history)
        bf16x8 bfr[4];
        #pragma unroll
        for (int ks = 0; ks < 4; ++ks)
            #pragma unroll
            for (int e = 0; e < 4; ++e) {
                bfr[ks][e]     = f2bf_hw(h0[ks][e]);
                bfr[ks][e + 4] = f2bf_hw(h1[ks][e]);
            }
        // swapped MFMA: D[n,s]; A = W'' frags (LDS), B = history frags
        f32x4 acc[4];
        #pragma unroll
        for (int ng = 0; ng < 4; ++ng) acc[ng] = (f32x4){0.f, 0.f, 0.f, 0.f};
        #pragma unroll
        for (int ks = 0; ks < 4; ++ks)
            #pragma unroll
            for (int ng = 0; ng < 4; ++ng) {
                bf16x8 af = *(const bf16x8*)(L + abase[ng] + akoff[ks]);
                acc[ng] = __builtin_amdgcn_mfma_f32_16x16x32_bf16(af, bfr[ks], acc[ng], 0, 0, 0);
            }
        // lane-local relu-dot over this lane's 16 n-values; s = t*16+lo
        float s0 = 0.f, s1 = 0.f, s2 = 0.f, s3 = 0.f;
        #pragma unroll
        for (int e = 0; e < 4; ++e) {
            s0 = fmaf(fmaxf(acc[0][e] + tav[0][e], 0.f), w2v[0][e], s0);
            s1 = fmaf(fmaxf(acc[1][e] + tav[1][e], 0.f), w2v[1][e], s1);
            s2 = fmaf(fmaxf(acc[2][e] + tav[2][e], 0.f), w2v[2][e], s2);
            s3 = fmaf(fmaxf(acc[3][e] + tav[3][e], 0.f), w2v[3][e], s3);
        }
        float sum = (s0 + s1) + (s2 + s3);
        sum += __shfl_xor(sum, 16);
        sum += __shfl_xor(sum, 32);
        const int mv = (mbits >> t) & 1;
        float lg = mv ? sum : -1e30f;
        float tm = lg;
        tm = fmaxf(tm, __shfl_xor(tm, 1));
        tm = fmaxf(tm, __shfl_xor(tm, 2));
        tm = fmaxf(tm, __shfl_xor(tm, 4));
        tm = fmaxf(tm, __shfl_xor(tm, 8));
        if (tm > m2 + 11.5f) {                 // defer-rescale (T13)
            float r = exp2f(m2 - tm);
            #pragma unroll
            for (int ks = 0; ks < 4; ++ks)
                #pragma unroll
                for (int e = 0; e < 8; ++e) o[ks][e] *= r;
            l *= r;
            m2 = tm;
        }
        float p = mv ? exp2f(lg - m2) : 0.f;
        l += p;
        #pragma unroll
        for (int ks = 0; ks < 4; ++ks) {
            o[ks][0] = fmaf(p, h0[ks][0], o[ks][0]);
            o[ks][1] = fmaf(p, h0[ks][1], o[ks][1]);
            o[ks][2] = fmaf(p, h0[ks][2], o[ks][2]);
            o[ks][3] = fmaf(p, h0[ks][3], o[ks][3]);
            o[ks][4] = fmaf(p, h1[ks][0], o[ks][4]);
            o[ks][5] = fmaf(p, h1[ks][1], o[ks][5]);
            o[ks][6] = fmaf(p, h1[ks][2], o[ks][6]);
            o[ks][7] = fmaf(p, h1[ks][3], o[ks][7]);
        }
    };

    // --- 13-tile pipeline, 3-deep: two tiles always in flight; tail counts down ---
    int bo = 16384;
    #pragma unroll 1
    for (int t = 0; t < 11; ++t) {
        asm volatile("s_waitcnt vmcnt(16)" ::: "memory");   // tile t landed; t+1,t+2 in flight
        compt(t, bo, t + 3 < NT);
        bo += 8192; if (bo > 32768) bo = 16384;
    }
    asm volatile("s_waitcnt vmcnt(8)" ::: "memory");        // tile 11 landed
    compt(11, bo, false);
    bo += 8192; if (bo > 32768) bo = 16384;
    asm volatile("s_waitcnt vmcnt(0)" ::: "memory");        // tile 12 landed
    compt(12, bo, false);

    // --- epilogue: reduce over the 16 lo-lanes, direct stores ---
    #pragma unroll
    for (int ks = 0; ks < 4; ++ks)
        #pragma unroll
        for (int e = 0; e < 8; ++e) {
            float v = o[ks][e];
            v += __shfl_xor(v, 1);
            v += __shfl_xor(v, 2);
            v += __shfl_xor(v, 4);
            v += __shfl_xor(v, 8);
            o[ks][e] = v;
        }
    l += __shfl_xor(l, 1);
    l += __shfl_xor(l, 2);
    l += __shfl_xor(l, 4);
    l += __shfl_xor(l, 8);

    const float inv = 1.0f / l;                 // m2, b2 cancel in softmax
    if (lo == 0) {
        float* op = out + (size_t)b * D_ + hi * 8;
        #pragma unroll
        for (int ks = 0; ks < 4; ++ks) {
            f32x4 v0 = {o[ks][0] * inv, o[ks][1] * inv, o[ks][2] * inv, o[ks][3] * inv};
            f32x4 v1 = {o[ks][4] * inv, o[ks][5] * inv, o[ks][6] * inv, o[ks][7] * inv};
            *(f32x4*)(op + ks * 32)     = v0;
            *(f32x4*)(op + ks * 32 + 4) = v1;
        }
    }
}

extern "C" void kernel_launch(void* const* d_in, const int* in_sizes, int n_in,
                              void* d_out, int out_size, void* d_ws, size_t ws_size,
                              hipStream_t stream) {
    const float* tgt  = (const float*)d_in[0];
    const float* hist = (const float*)d_in[1];
    const int*   mask = (const int*)d_in[2];
    const float* W1   = (const float*)d_in[3];
    const float* b1   = (const float*)d_in[4];
    const float* W2   = (const float*)d_in[5];
    const float* b2   = (const float*)d_in[6];
    (void)b2;  // cancels in softmax
    float* out = (float*)d_out;
    char* ws = (char*)d_ws;

    prep_fold<<<64, 128, 0, stream>>>(W1, ws);
    prep_ta<<<B_ / 4, 256, 0, stream>>>(tgt, b1, ws);
    din_fused<<<B_, 64, 0, stream>>>(tgt, hist, mask, W2, ws, out);
}

// Round 11
// 63.659 us; speedup vs baseline: 1.5490x; 1.0763x over previous
//
#include <hip/hip_runtime.h>
#include <hip/hip_bf16.h>

typedef __attribute__((ext_vector_type(8))) short bf16x8;
typedef __attribute__((ext_vector_type(4))) float f32x4;

#define B_ 2048
#define S_ 200
#define D_ 128
#define H_ 64
#define NT 13
#define LOG2E 1.44269504f

// ws layout
#define WS_TA 0u                        // f32 tA[2048][64]          = 512 KB
#define WS_AC (512u*1024u)              // f32 acT[64][128] (W1a+W1c)=  32 KB
#define WS_BC (512u*1024u + 32768u)     // f32 bcT[64][128] (W1b-W1c)=  32 KB
#define WS_DT (512u*1024u + 65536u)     // f32 dT [64][128] (W1d)    =  32 KB

static __device__ __forceinline__ short f2bf_hw(float f) {
    return (short)__builtin_bit_cast(unsigned short, __float2bfloat16(f));  // RNE
}

static __device__ __forceinline__ void gload16(const void* g, void* l) {
    // LDS dest = wave-uniform base + lane*16 ; global addr is per-lane
    __builtin_amdgcn_global_load_lds(
        (const __attribute__((address_space(1))) unsigned int*)g,
        (__attribute__((address_space(3))) unsigned int*)l, 16, 0, 0);
}

// ---- prep A: fold + transpose W1 into acT/bcT/dT (k-contiguous) ----
__global__ __launch_bounds__(128)
void prep_fold(const float* __restrict__ W1, char* __restrict__ ws)
{
    const int n = blockIdx.x;       // 64 blocks
    const int k = threadIdx.x;      // 128 threads
    float a = W1[k * H_ + n];
    float b = W1[(128 + k) * H_ + n];
    float c = W1[(256 + k) * H_ + n];
    float d = W1[(384 + k) * H_ + n];
    ((float*)(ws + WS_AC))[n * 128 + k] = a + c;
    ((float*)(ws + WS_BC))[n * 128 + k] = b - c;
    ((float*)(ws + WS_DT))[n * 128 + k] = d;
}

// ---- prep B: exact fp32 tA[b][n] = t.(W1a+W1c) + b1 ; 4 batches per block ----
__global__ __launch_bounds__(256)
void prep_ta(const float* __restrict__ tgt, const float* __restrict__ b1,
             char* __restrict__ ws)
{
    __shared__ float tl[4][128];
    const int tid = threadIdx.x;
    const int b0 = blockIdx.x * 4;
    if (tid < 128) {
        int bb = tid >> 5, q = tid & 31;
        *(float4*)&tl[bb][q * 4] = ((const float4*)(tgt + (size_t)(b0 + bb) * D_))[q];
    }
    __syncthreads();
    const int n = tid & 63, bb = tid >> 6;
    const float* ac = (const float*)(ws + WS_AC) + n * 128;
    float s = 0.f;
    #pragma unroll 8
    for (int d = 0; d < 128; ++d) s = fmaf(tl[bb][d], ac[d], s);
    ((float*)(ws + WS_TA))[(size_t)(b0 + bb) * H_ + n] = s + b1[n];
}

// ---- fused: block = batch; 4 waves share W'' and split the 13 tiles (4/3/3/3).
// LDS 80 KB: [0,16K) W'' ; wave wv hist bufs at 16K + wv*16K + {0,8K}.
// 2 blocks/CU -> 8 waves/CU = 2 waves/SIMD (the R10 structure had 1/SIMD).
__global__ __launch_bounds__(256) __attribute__((amdgpu_waves_per_eu(2, 2)))
void din_fused(const float* __restrict__ tgt, const float* __restrict__ hist,
               const int* __restrict__ mask, const float* __restrict__ W2,
               const char* __restrict__ ws, float* __restrict__ out)
{
    __shared__ __align__(16) char L[81920];
    const int tid  = threadIdx.x;
    const int lane = tid & 63;
    const int wv   = tid >> 6;
    const int b    = blockIdx.x;
    const int lo   = lane & 15;
    const int hi   = lane >> 4;

    // --- per-lane prologue loads (drained by the build barrier) ---
    const int ntile = (wv == 0) ? 4 : 3;     // tiles wv, wv+4, wv+8 [, 12]
    int mv_[4];
    {
        const int* mp = mask + (size_t)b * S_;
        #pragma unroll
        for (int i = 0; i < 4; ++i) {
            int t = wv + 4 * i;
            int s = (t << 4) + lo;
            mv_[i] = 0;
            if (i < ntile && s < S_) mv_[i] = mp[s];
        }
    }
    f32x4 tav[4], w2v[4];
    #pragma unroll
    for (int ng = 0; ng < 4; ++ng) {
        tav[ng] = *(const f32x4*)((const float*)(ws + WS_TA) + (size_t)b * H_ + ng * 16 + hi * 4);
        f32x4 wl = *(const f32x4*)(W2 + ng * 16 + hi * 4);
        w2v[ng] = (f32x4){wl[0] * LOG2E, wl[1] * LOG2E, wl[2] * LOG2E, wl[3] * LOG2E};
    }

    // --- cooperative W'' build: 1024 chunks / 256 threads = 4 each ---
    // W''[k][n] = (W1b-W1c)[k][n] + t[k]*W1d[k][n], bf16, [n][k] XOR-swizzled.
    {
        const float* bcT = (const float*)(ws + WS_BC);
        const float* dT  = (const float*)(ws + WS_DT);
        const int kb = tid & 15;             // fixed k-octet per thread
        f32x4 t0 = *(const f32x4*)(tgt + (size_t)b * D_ + kb * 8);
        f32x4 t1 = *(const f32x4*)(tgt + (size_t)b * D_ + kb * 8 + 4);
        #pragma unroll
        for (int j = 0; j < 4; ++j) {
            int n = (tid >> 4) + j * 16;
            f32x4 bc0 = *(const f32x4*)(bcT + n * 128 + kb * 8);
            f32x4 bc1 = *(const f32x4*)(bcT + n * 128 + kb * 8 + 4);
            f32x4 dd0 = *(const f32x4*)(dT  + n * 128 + kb * 8);
            f32x4 dd1 = *(const f32x4*)(dT  + n * 128 + kb * 8 + 4);
            bf16x8 v;
            #pragma unroll
            for (int e = 0; e < 4; ++e) {
                v[e]     = f2bf_hw(fmaf(t0[e], dd0[e], bc0[e]));
                v[e + 4] = f2bf_hw(fmaf(t1[e], dd1[e], bc1[e]));
            }
            *(bf16x8*)(L + n * 256 + ((kb * 16) ^ ((n & 7) << 4))) = v;
        }
    }
    __syncthreads();   // W'' visible; drains prologue vmem (no stage glls yet)

    // --- addresses ---
    int abase[4], akoff[4];
    #pragma unroll
    for (int ng = 0; ng < 4; ++ng) abase[ng] = (ng * 16 + lo) * 256;
    #pragma unroll
    for (int ks = 0; ks < 4; ++ks) akoff[ks] = (ks * 64 + hi * 16) ^ ((lo & 7) << 4);
    const int rb = (lo * 512 + hi * 32) ^ ((lo & 7) << 4);
    char* B0 = L + 16384 + (wv << 14);
    char* B1 = B0 + 8192;

    const char* hb = (const char*)hist + (size_t)b * (S_ * D_ * 4);
    const int cp = (lane & 31) * 16;
    const int h5 = lane >> 5;
    auto stage = [&](int t, char* bufp) {
        #pragma unroll
        for (int i = 0; i < 8; ++i) {
            int r = 2 * i + h5;
            int s = (t << 4) + r;
            s = s > S_ - 1 ? S_ - 1 : s;
            gload16(hb + s * 512 + (cp ^ ((r & 7) << 4)), bufp + i * 1024);
        }
    };
    stage(wv, B0);
    stage(wv + 4, B1);

    float o[4][8];
    #pragma unroll
    for (int ks = 0; ks < 4; ++ks)
        #pragma unroll
        for (int e = 0; e < 8; ++e) o[ks][e] = 0.f;
    float l = 0.f, mx = -1e30f;

    auto compt = [&](int mv, char* buf, int stage_t) {
        // QK: per-ks jit cvt keeps liveness low
        f32x4 acc[4];
        #pragma unroll
        for (int ng = 0; ng < 4; ++ng) acc[ng] = (f32x4){0.f, 0.f, 0.f, 0.f};
        #pragma unroll
        for (int ks = 0; ks < 4; ++ks) {
            int o4 = rb + ks * 128;
            f32x4 h0 = *(const f32x4*)(buf + o4);
            f32x4 h1 = *(const f32x4*)(buf + (o4 ^ 16));
            bf16x8 bfr;
            #pragma unroll
            for (int e = 0; e < 4; ++e) {
                bfr[e]     = f2bf_hw(h0[e]);
                bfr[e + 4] = f2bf_hw(h1[e]);
            }
            #pragma unroll
            for (int ng = 0; ng < 4; ++ng) {
                bf16x8 af = *(const bf16x8*)(L + abase[ng] + akoff[ks]);
                acc[ng] = __builtin_amdgcn_mfma_f32_16x16x32_bf16(af, bfr, acc[ng], 0, 0, 0);
            }
        }
        // lane-local relu-dot over this lane's 16 n-values; s = t*16+lo
        float s0 = 0.f, s1 = 0.f, s2 = 0.f, s3 = 0.f;
        #pragma unroll
        for (int e = 0; e < 4; ++e) {
            s0 = fmaf(fmaxf(acc[0][e] + tav[0][e], 0.f), w2v[0][e], s0);
            s1 = fmaf(fmaxf(acc[1][e] + tav[1][e], 0.f), w2v[1][e], s1);
            s2 = fmaf(fmaxf(acc[2][e] + tav[2][e], 0.f), w2v[2][e], s2);
            s3 = fmaf(fmaxf(acc[3][e] + tav[3][e], 0.f), w2v[3][e], s3);
        }
        float sum = (s0 + s1) + (s2 + s3);
        sum += __shfl_xor(sum, 16);
        sum += __shfl_xor(sum, 32);
        float lg = mv ? sum : -1e30f;
        float tm = lg;
        tm = fmaxf(tm, __shfl_xor(tm, 1));
        tm = fmaxf(tm, __shfl_xor(tm, 2));
        tm = fmaxf(tm, __shfl_xor(tm, 4));
        tm = fmaxf(tm, __shfl_xor(tm, 8));
        if (tm > mx + 11.5f) {                 // defer-rescale (T13)
            float r = exp2f(mx - tm);
            #pragma unroll
            for (int ks = 0; ks < 4; ++ks)
                #pragma unroll
                for (int e = 0; e < 8; ++e) o[ks][e] *= r;
            l *= r;
            mx = tm;
        }
        float p = mv ? exp2f(lg - mx) : 0.f;
        l += p;
        // PV: re-read history (keeps regs small across the softmax chain)
        f32x4 ph0[4], ph1[4];
        #pragma unroll
        for (int ks = 0; ks < 4; ++ks) {
            int o4 = rb + ks * 128;
            ph0[ks] = *(const f32x4*)(buf + o4);
            ph1[ks] = *(const f32x4*)(buf + (o4 ^ 16));
        }
        asm volatile("s_waitcnt lgkmcnt(0)" ::: "memory");
        __builtin_amdgcn_sched_barrier(0);
        if (stage_t >= 0) stage(stage_t, buf);   // buf's reads retired; overwrite ok
        #pragma unroll
        for (int ks = 0; ks < 4; ++ks) {
            o[ks][0] = fmaf(p, ph0[ks][0], o[ks][0]);
            o[ks][1] = fmaf(p, ph0[ks][1], o[ks][1]);
            o[ks][2] = fmaf(p, ph0[ks][2], o[ks][2]);
            o[ks][3] = fmaf(p, ph0[ks][3], o[ks][3]);
            o[ks][4] = fmaf(p, ph1[ks][0], o[ks][4]);
            o[ks][5] = fmaf(p, ph1[ks][1], o[ks][5]);
            o[ks][6] = fmaf(p, ph1[ks][2], o[ks][6]);
            o[ks][7] = fmaf(p, ph1[ks][3], o[ks][7]);
        }
    };

    // --- per-wave pipeline over its tiles (2-deep, counted vmcnt) ---
    asm volatile("s_waitcnt vmcnt(8)" ::: "memory");    // tile wv landed
    compt(mv_[0], B0, wv + 8);                          // prefetch 3rd tile
    if (wv == 0) {
        asm volatile("s_waitcnt vmcnt(8)" ::: "memory");
        compt(mv_[1], B1, 12);                          // prefetch 4th tile
        asm volatile("s_waitcnt vmcnt(8)" ::: "memory");
        compt(mv_[2], B0, -1);
        asm volatile("s_waitcnt vmcnt(0)" ::: "memory");
        compt(mv_[3], B1, -1);
    } else {
        asm volatile("s_waitcnt vmcnt(8)" ::: "memory");
        compt(mv_[1], B1, -1);
        asm volatile("s_waitcnt vmcnt(0)" ::: "memory");
        compt(mv_[2], B0, -1);
    }

    // --- per-wave lo-reduce, publish to own buffer area, 4-way flash merge ---
    #pragma unroll
    for (int ks = 0; ks < 4; ++ks)
        #pragma unroll
        for (int e = 0; e < 8; ++e) {
            float v = o[ks][e];
            v += __shfl_xor(v, 1);
            v += __shfl_xor(v, 2);
            v += __shfl_xor(v, 4);
            v += __shfl_xor(v, 8);
            o[ks][e] = v;
        }
    l += __shfl_xor(l, 1);
    l += __shfl_xor(l, 2);
    l += __shfl_xor(l, 4);
    l += __shfl_xor(l, 8);

    float* mo = (float*)B0;                    // wave-private, loop done
    if (lo == 0) {
        #pragma unroll
        for (int ks = 0; ks < 4; ++ks) {
            *(f32x4*)(mo + ks * 32 + hi * 8)     = (f32x4){o[ks][0], o[ks][1], o[ks][2], o[ks][3]};
            *(f32x4*)(mo + ks * 32 + hi * 8 + 4) = (f32x4){o[ks][4], o[ks][5], o[ks][6], o[ks][7]};
        }
        if (hi == 0) { mo[128] = mx; mo[129] = l; }
    }
    __syncthreads();

    if (tid < 128) {
        const float* m0 = (const float*)(L + 16384);
        const float* m1 = (const float*)(L + 16384 + 16384);
        const float* m2 = (const float*)(L + 16384 + 32768);
        const float* m3 = (const float*)(L + 16384 + 49152);
        float mstar = fmaxf(fmaxf(m0[128], m1[128]), fmaxf(m2[128], m3[128]));
        float f0 = exp2f(m0[128] - mstar), f1 = exp2f(m1[128] - mstar);
        float f2 = exp2f(m2[128] - mstar), f3 = exp2f(m3[128] - mstar);
        float num = m0[tid] * f0 + m1[tid] * f1 + m2[tid] * f2 + m3[tid] * f3;
        float den = m0[129] * f0 + m1[129] * f1 + m2[129] * f2 + m3[129] * f3;
        out[(size_t)b * D_ + tid] = num / den;   // b2 cancels in softmax
    }
}

extern "C" void kernel_launch(void* const* d_in, const int* in_sizes, int n_in,
                              void* d_out, int out_size, void* d_ws, size_t ws_size,
                              hipStream_t stream) {
    const float* tgt  = (const float*)d_in[0];
    const float* hist = (const float*)d_in[1];
    const int*   mask = (const int*)d_in[2];
    const float* W1   = (const float*)d_in[3];
    const float* b1   = (const float*)d_in[4];
    const float* W2   = (const float*)d_in[5];
    const float* b2   = (const float*)d_in[6];
    (void)b2;  // cancels in softmax
    float* out = (float*)d_out;
    char* ws = (char*)d_ws;

    prep_fold<<<64, 128, 0, stream>>>(W1, ws);
    prep_ta<<<B_ / 4, 256, 0, stream>>>(tgt, b1, ws);
    din_fused<<<B_, 256, 0, stream>>>(tgt, hist, mask, W2, ws, out);
}